// Round 14
// baseline (259.285 us; speedup 1.0000x reference)
//
#include <hip/hip_runtime.h>
#include <hip/hip_fp16.h>

#define N_NODES 50000
#define N_EDGES 800000
#define N_OBS   4
#define HID     64
#define K_HOPS  5
#define ROW     (N_OBS * HID)   // 256 elements per node
#define NHALF   (N_NODES / 2)
#define NSCAN2_BLKS ((2 * N_NODES + 1023) / 1024)   // 98

typedef _Float16 f16x8 __attribute__((ext_vector_type(8)));
typedef _Float16 f16x4 __attribute__((ext_vector_type(4)));
typedef float    f32x4 __attribute__((ext_vector_type(4)));

// ---------------------------------------------------------------- zero
__global__ void zero_kernel(int* __restrict__ p, int n) {
    int i = blockIdx.x * blockDim.x + threadIdx.x;
    if (i < n) p[i] = 0;
}

// ---------------------------------------------------------------- histogram over (src-half, dst) + per-edge rank (u16)
__global__ void hist_kernel(const int* __restrict__ src, const int* __restrict__ dst,
                            int* __restrict__ cnt2, unsigned short* __restrict__ erank) {
    int e = blockIdx.x * blockDim.x + threadIdx.x;
    if (e < N_EDGES) {
        int half = (src[e] >= NHALF) ? 1 : 0;
        erank[e] = (unsigned short)atomicAdd(&cnt2[half * N_NODES + dst[e]], 1);
    }
}

// ---------------------------------------------------------------- scan pass 1: per-block sums (over 2N counts)
__global__ __launch_bounds__(1024) void scan1_kernel(const int* __restrict__ counts,
                                                     int* __restrict__ bsum) {
    __shared__ int wsum[16];
    const int t = threadIdx.x, lane = t & 63, wid = t >> 6;
    int i = blockIdx.x * 1024 + t;
    int x = (i < 2 * N_NODES) ? counts[i] : 0;
    #pragma unroll
    for (int off = 32; off > 0; off >>= 1) x += __shfl_xor(x, off);
    if (lane == 0) wsum[wid] = x;
    __syncthreads();
    if (t == 0) {
        int s = 0;
        #pragma unroll
        for (int j = 0; j < 16; ++j) s += wsum[j];
        bsum[blockIdx.x] = s;
    }
}

// ---------------------------------------------------------------- scan pass 2: exclusive scan of 98 block sums (2 waves)
__global__ void scan2_kernel(int* __restrict__ bsum) {
    const int t = threadIdx.x;   // 128 threads
    const int lane = t & 63, w = t >> 6;
    __shared__ int w0tot;
    int v = (t < NSCAN2_BLKS) ? bsum[t] : 0;
    int x = v;
    #pragma unroll
    for (int off = 1; off < 64; off <<= 1) {
        int y = __shfl_up(x, off);
        if (lane >= off) x += y;
    }
    if (t == 63) w0tot = x;
    __syncthreads();
    if (w == 1) x += w0tot;
    if (t < NSCAN2_BLKS) bsum[t] = x - v;   // exclusive
}

// ---------------------------------------------------------------- scan pass 3: full offsets (2N+1)
__global__ __launch_bounds__(1024) void scan3_kernel(const int* __restrict__ counts,
                                                     const int* __restrict__ bsum,
                                                     int* __restrict__ offsets) {
    __shared__ int wsum[16];
    __shared__ int wpre[16];
    const int t = threadIdx.x, lane = t & 63, wid = t >> 6;
    int i = blockIdx.x * 1024 + t;
    int v = (i < 2 * N_NODES) ? counts[i] : 0;
    int x = v;
    #pragma unroll
    for (int off = 1; off < 64; off <<= 1) {
        int y = __shfl_up(x, off);
        if (lane >= off) x += y;
    }
    if (lane == 63) wsum[wid] = x;
    __syncthreads();
    if (t < 16) {
        int p = 0;
        for (int j = 0; j < t; ++j) p += wsum[j];
        wpre[t] = p;
    }
    __syncthreads();
    int base = bsum[blockIdx.x];
    int incl = base + x + wpre[wid];
    if (i < 2 * N_NODES) offsets[i + 1] = incl;
    if (i == 0) offsets[0] = 0;
}

// ---------------------------------------------------------------- scatter edges into split-CSR order (atomic-free)
__global__ void scatter_kernel(const int* __restrict__ src, const int* __restrict__ dst,
                               const float* __restrict__ w, const int* __restrict__ offsets,
                               const unsigned short* __restrict__ erank,
                               unsigned int* __restrict__ ecmp) {
    int e = blockIdx.x * blockDim.x + threadIdx.x;
    if (e < N_EDGES) {
        int s = src[e];
        int half = (s >= NHALF) ? 1 : 0;
        int p = offsets[half * N_NODES + dst[e]] + (int)erank[e];
        __half hw = __float2half(w[e]);
        ecmp[p] = ((unsigned int)__half_as_ushort(hw) << 16) | (unsigned int)s;
    }
}

// ---------------------------------------------------------------- pack W_hop into MFMA B-fragment order (f16)
__global__ void packW_kernel(const float* __restrict__ W, _Float16* __restrict__ Bp) {
    int i = blockIdx.x * 256 + threadIdx.x;   // 0..4095
    if (i >= 4096) return;
    int j  = i & 7;
    int l  = (i >> 3) & 63;
    int ks = (i >> 9) & 1;
    int w  = i >> 10;
    int k   = ks * 32 + ((j >> 2) * 16) + ((l >> 4) * 4) + (j & 3);
    int col = w * 16 + (l & 15);
    Bp[i] = (_Float16)W[k * 64 + col];
}

// ---------------------------------------------------------------- WlW[j] = sum_h Wl[h]*W[h,j]; blW[j] = sum_h bl[h]*W[h,j]
__global__ void wlw_kernel(const float* __restrict__ Wl, const float* __restrict__ bl,
                           const float* __restrict__ W, float* __restrict__ WlW,
                           float* __restrict__ blW) {
    int j = threadIdx.x;   // 64 threads
    float a = 0.f, b = 0.f;
    #pragma unroll 8
    for (int h = 0; h < 64; ++h) {
        float wv = W[h * 64 + j];
        a += Wl[h] * wv;
        b += bl[h] * wv;
    }
    WlW[j] = a;
    blW[j] = b;
}

// ---------------------------------------------------------------- hop-1 scalar gather: t[d,o]=sum w*nodes[s,o], u[d]=sum w
__global__ void hop1_gather_kernel(const int* __restrict__ offsets,
                                   const unsigned int* __restrict__ ecmp,
                                   const float* __restrict__ nodes,
                                   float4* __restrict__ T, float* __restrict__ U) {
    int n = blockIdx.x * blockDim.x + threadIdx.x;
    if (n >= N_NODES) return;
    float4 t = {0.f, 0.f, 0.f, 0.f};
    float u = 0.f;
    #pragma unroll
    for (int h2 = 0; h2 < 2; ++h2) {
        int s = offsets[h2 * N_NODES + n];
        int e = offsets[h2 * N_NODES + n + 1];
        for (int i = s; i < e; ++i) {
            unsigned int p = ecmp[i];
            float w = __half2float(__ushort_as_half((unsigned short)(p >> 16)));
            int sn = (int)(p & 0xffffu);
            float4 nv = ((const float4*)nodes)[sn];
            t.x += w * nv.x; t.y += w * nv.y; t.z += w * nv.z; t.w += w * nv.w;
            u += w;
        }
    }
    T[n] = t;
    U[n] = u;
}

// ---------------------------------------------------------------- hop-1 finish into obs-sliced X[o][n][h] f16
__global__ void hop1_finish_kernel(const float4* __restrict__ T, const float* __restrict__ U,
                                   const float* __restrict__ WlW, const float* __restrict__ blW,
                                   const float* __restrict__ bias, _Float16* __restrict__ X) {
    int i = blockIdx.x * blockDim.x + threadIdx.x;   // 4-elem group
    const int total = N_NODES * ROW / 4;
    if (i >= total) return;
    int n   = i >> 6;
    int rem = i & 63;
    int o   = rem >> 4;
    int h4  = rem & 15;
    float t = ((const float*)&T[n])[o];
    float u = U[n];
    float4 wv = ((const float4*)WlW)[h4];
    float4 bv = ((const float4*)blW)[h4];
    float4 hv = ((const float4*)bias)[h4];
    f16x4 st;
    st[0] = (_Float16)fmaxf(t * wv.x + u * bv.x + hv.x, 0.f);
    st[1] = (_Float16)fmaxf(t * wv.y + u * bv.y + hv.y, 0.f);
    st[2] = (_Float16)fmaxf(t * wv.z + u * bv.z + hv.z, 0.f);
    st[3] = (_Float16)fmaxf(t * wv.w + u * bv.w + hv.w, 0.f);
    *(f16x4*)(X + ((size_t)o * N_NODES + n) * 64 + h4 * 4) = st;
}

// ---------------------------------------------------------------- fused hop, obs-sliced + src-half-split gather:
// X layout [4][N][64 f16] (128B rows). blockIdx&7 -> XCD; obs = xcd>>1.
// Edge lists split by src-half (two CSR sections): phase A touches only the
// lower 3.2MB of the slice, phase B the upper -> each phase L2-resident.
// 8 lanes/node, unroll-8 rounds (8 row loads in flight); pk_fma f16 accum;
// 16 MFMAs/block; LDS-staged coalesced epilogue.
template<int LAST>
__global__ __launch_bounds__(256) void hop_kernel(const int* __restrict__ offsets,
                                                  const unsigned int* __restrict__ ecmp,
                                                  const _Float16* __restrict__ Xin,
                                                  const _Float16* __restrict__ Bp,
                                                  const float* __restrict__ bias,
                                                  _Float16* __restrict__ Xout,
                                                  float* __restrict__ Fout) {
    __shared__ __align__(16) char smem[32 * 68 * 4];     // 8704 B, aliased
    _Float16 (*As)[72]  = (_Float16(*)[72])smem;         // gather stage + f16 epilogue
    float    (*Asf)[68] = (float(*)[68])smem;            // f32 epilogue (LAST)

    const int t = threadIdx.x;
    const int wid = t >> 6, lane = t & 63;
    const int b = blockIdx.x;
    const int xcd = b & 7;
    const int o = xcd >> 1;                  // obs slice pinned to XCD pair
    const int g = ((b >> 3) << 1) | (xcd & 1);
    const int n0 = g * 32;
    if (n0 >= N_NODES) return;

    const int g8  = lane >> 3;               // node group within wave (0..7)
    const int sub = lane & 7;                // 16B chunk of the 128B row
    const int local = wid * 8 + g8;          // 0..31
    const int node = n0 + local;
    const int nc = (node < N_NODES) ? node : N_NODES - 1;
    const int sA = offsets[nc];
    const int eA = offsets[nc + 1];
    const int sB = offsets[N_NODES + nc];
    const int eB = offsets[N_NODES + nc + 1];
    const int degA = (node < N_NODES) ? (eA - sA) : 0;
    const int degB = (node < N_NODES) ? (eB - sB) : 0;

    const _Float16* __restrict__ Xb = Xin + (size_t)o * (N_NODES * 64);

    f16x8 acc0 = (f16x8)(_Float16)0.0f;
    f16x8 acc1 = (f16x8)(_Float16)0.0f;

    #pragma unroll
    for (int h2 = 0; h2 < 2; ++h2) {
        const int sN  = h2 ? sB : sA;
        const int deg = h2 ? degB : degA;
        for (int base = 0; base < deg; base += 8) {
            f16x8 r[8];
            _Float16 wh[8];
            #pragma unroll
            for (int q = 0; q < 8; ++q) {
                int idx = base + q;
                int e = sN + ((idx < deg) ? idx : 0);    // clamped: pad slots reload edge 0
                unsigned int p = ecmp[e];
                unsigned short wu = (idx < deg) ? (unsigned short)(p >> 16) : (unsigned short)0;
                wh[q] = __builtin_bit_cast(_Float16, wu);
                r[q] = *(const f16x8*)(Xb + (int)(p & 0xffffu) * 64 + sub * 8);
            }
            #pragma unroll
            for (int q = 0; q < 8; q += 2) {
                acc0 += r[q]     * wh[q];
                acc1 += r[q + 1] * wh[q + 1];
            }
        }
    }
    acc0 += acc1;
    *(f16x8*)&As[local][sub * 8] = acc0;
    __syncthreads();

    // wave: node-tile nt = wid>>1 (16 nodes), col-tiles ct0, ct0+1 (32 hid)
    const int r15 = lane & 15, gq = lane >> 4;
    const int nt  = wid >> 1;
    const int ct0 = (wid & 1) * 2;
    const int arow = nt * 16 + r15;
    f16x8 a0, a1;
    ((f16x4*)&a0)[0] = *(const f16x4*)&As[arow][ 0 + 4 * gq];
    ((f16x4*)&a0)[1] = *(const f16x4*)&As[arow][16 + 4 * gq];
    ((f16x4*)&a1)[0] = *(const f16x4*)&As[arow][32 + 4 * gq];
    ((f16x4*)&a1)[1] = *(const f16x4*)&As[arow][48 + 4 * gq];
    float res[2][4];
    #pragma unroll
    for (int c = 0; c < 2; ++c) {
        const int ct = ct0 + c;
        f16x8 b0 = *(const f16x8*)(Bp + ((size_t)(ct * 2 + 0) * 64 + lane) * 8);
        f16x8 b1 = *(const f16x8*)(Bp + ((size_t)(ct * 2 + 1) * 64 + lane) * 8);
        f32x4 cc = {0.f, 0.f, 0.f, 0.f};
        cc = __builtin_amdgcn_mfma_f32_16x16x32_f16(a0, b0, cc, 0, 0, 0);
        cc = __builtin_amdgcn_mfma_f32_16x16x32_f16(a1, b1, cc, 0, 0, 0);
        const float bv = bias[ct * 16 + r15];
        #pragma unroll
        for (int j = 0; j < 4; ++j) res[c][j] = fmaxf(cc[j] + bv, 0.f);
    }
    __syncthreads();   // all frag loads done; safe to overwrite LDS

    // stage results: row = local node (nt*16+gq*4+j), col = h (ct*16+r15)
    #pragma unroll
    for (int c = 0; c < 2; ++c) {
        const int h = (ct0 + c) * 16 + r15;
        #pragma unroll
        for (int j = 0; j < 4; ++j) {
            int ln = nt * 16 + gq * 4 + j;
            if (LAST) Asf[ln][h] = res[c][j];
            else      As[ln][h]  = (_Float16)res[c][j];
        }
    }
    __syncthreads();

    // coalesced write-out: 8 lanes per node row
    const int wl = t >> 3;       // local node 0..31
    const int wsc = t & 7;       // 8-elem chunk
    const int wnode = n0 + wl;
    if (wnode < N_NODES) {
        if (LAST) {
            float4 v0 = *(const float4*)&Asf[wl][wsc * 8];
            float4 v1 = *(const float4*)&Asf[wl][wsc * 8 + 4];
            float* dst = Fout + (size_t)wnode * ROW + o * 64 + wsc * 8;
            *(float4*)dst       = v0;
            *(float4*)(dst + 4) = v1;
        } else {
            f16x8 v = *(const f16x8*)&As[wl][wsc * 8];
            *(f16x8*)(Xout + ((size_t)o * N_NODES + wnode) * 64 + wsc * 8) = v;
        }
    }
}

// ---------------------------------------------------------------- launch
extern "C" void kernel_launch(void* const* d_in, const int* in_sizes, int n_in,
                              void* d_out, int out_size, void* d_ws, size_t ws_size,
                              hipStream_t stream) {
    const float* nodes   = (const float*)d_in[0];
    const int*   esrc    = (const int*)d_in[1];
    const int*   edst    = (const int*)d_in[2];
    const float* eweight = (const float*)d_in[3];
    const float* W_lift  = (const float*)d_in[4];
    const float* b_lift  = (const float*)d_in[5];
    const float* W_hop   = (const float*)d_in[6];
    const float* b_hop   = (const float*)d_in[7];

    char* ws = (char*)d_ws;
    _Float16*       X0    = (_Float16*)(ws);                  // 25,600,000 B
    _Float16*       X1    = (_Float16*)(ws + 25600000);       // 25,600,000 B
    unsigned int*   ECMP  = (unsigned int*)(ws + 51200000);   //  3,200,000 B
    int*            OFF   = (int*)(ws + 54400000);            //    400,008 B (2N+1)
    int*            CNT   = (int*)(ws + 54800064);            //    400,000 B (2N)
    int*            BSUM  = (int*)(ws + 55200064);            //        512 B
    _Float16*       BP    = (_Float16*)(ws + 55200576);       //      8,192 B
    float*          WLW   = (float*)(ws + 55208768);          //        256 B
    float*          BLW   = (float*)(ws + 55209024);          //        256 B
    // ERANK (u16) overlays T/U (disjoint lifetimes: ERANK dead after scatter)
    unsigned short* ERANK = (unsigned short*)(ws + 55209280); //  1,600,000 B
    float4*         T     = (float4*)(ws + 55209280);         //    800,000 B
    float*          U     = (float*)(ws + 56009280);          //    200,000 B

    // split-CSR build: hist over (src-half, dst); scatter atomic-free
    zero_kernel<<<(2 * N_NODES + 255) / 256, 256, 0, stream>>>(CNT, 2 * N_NODES);
    hist_kernel<<<(N_EDGES + 255) / 256, 256, 0, stream>>>(esrc, edst, CNT, ERANK);
    scan1_kernel<<<NSCAN2_BLKS, 1024, 0, stream>>>(CNT, BSUM);
    scan2_kernel<<<1, 128, 0, stream>>>(BSUM);
    scan3_kernel<<<NSCAN2_BLKS, 1024, 0, stream>>>(CNT, BSUM, OFF);
    scatter_kernel<<<(N_EDGES + 255) / 256, 256, 0, stream>>>(esrc, edst, eweight, OFF, ERANK, ECMP);

    // weight prep
    packW_kernel<<<16, 256, 0, stream>>>(W_hop, BP);
    wlw_kernel<<<1, 64, 0, stream>>>(W_lift, b_lift, W_hop, WLW, BLW);

    // hop 1 (algebraic: scalar gather + rank-1 reconstruction) -> X0 (obs-sliced)
    hop1_gather_kernel<<<(N_NODES + 255) / 256, 256, 0, stream>>>(OFF, ECMP, nodes, T, U);
    hop1_finish_kernel<<<(N_NODES * ROW / 4 + 255) / 256, 256, 0, stream>>>(T, U, WLW, BLW, b_hop, X0);

    // hops 2..5: fused obs-sliced gather+GEMM, double-buffered X
    const int hopGrid = 8 * 782;   // xcd-pinned: 4 obs x 1564 half-groups (32 nodes/blk)
    _Float16* Xi = X0;
    _Float16* Xo = X1;
    for (int hop = 1; hop < K_HOPS; ++hop) {
        if (hop == K_HOPS - 1) {
            hop_kernel<1><<<hopGrid, 256, 0, stream>>>(OFF, ECMP, Xi, BP, b_hop,
                                                       nullptr, (float*)d_out);
        } else {
            hop_kernel<0><<<hopGrid, 256, 0, stream>>>(OFF, ECMP, Xi, BP, b_hop,
                                                       Xo, nullptr);
        }
        _Float16* tmp = Xi; Xi = Xo; Xo = tmp;
    }
}

// Round 15
// 247.303 us; speedup vs baseline: 1.0485x; 1.0485x over previous
//
#include <hip/hip_runtime.h>
#include <hip/hip_fp16.h>

#define N_NODES 50000
#define N_EDGES 800000
#define N_OBS   4
#define HID     64
#define K_HOPS  5
#define ROW     (N_OBS * HID)   // 256 elements per node
#define NSCAN_BLKS ((N_NODES + 1023) / 1024)   // 49

typedef _Float16 f16x8 __attribute__((ext_vector_type(8)));
typedef _Float16 f16x4 __attribute__((ext_vector_type(4)));
typedef float    f32x4 __attribute__((ext_vector_type(4)));

// ---------------------------------------------------------------- zero
__global__ void zero_kernel(int* __restrict__ p, int n) {
    int i = blockIdx.x * blockDim.x + threadIdx.x;
    if (i < n) p[i] = 0;
}

// ---------------------------------------------------------------- histogram of dst + per-edge rank
__global__ void hist_kernel(const int* __restrict__ dst, int* __restrict__ cnt,
                            int* __restrict__ erank) {
    int e = blockIdx.x * blockDim.x + threadIdx.x;
    if (e < N_EDGES) erank[e] = atomicAdd(&cnt[dst[e]], 1);
}

// ---------------------------------------------------------------- scan pass 1: per-block sums
__global__ __launch_bounds__(1024) void scan1_kernel(const int* __restrict__ counts,
                                                     int* __restrict__ bsum) {
    __shared__ int wsum[16];
    const int t = threadIdx.x, lane = t & 63, wid = t >> 6;
    int i = blockIdx.x * 1024 + t;
    int x = (i < N_NODES) ? counts[i] : 0;
    #pragma unroll
    for (int off = 32; off > 0; off >>= 1) x += __shfl_xor(x, off);
    if (lane == 0) wsum[wid] = x;
    __syncthreads();
    if (t == 0) {
        int s = 0;
        #pragma unroll
        for (int j = 0; j < 16; ++j) s += wsum[j];
        bsum[blockIdx.x] = s;
    }
}

// ---------------------------------------------------------------- scan pass 2: exclusive scan of block sums (1 wave)
__global__ void scan2_kernel(int* __restrict__ bsum) {
    const int t = threadIdx.x;   // 64 threads
    int v = (t < NSCAN_BLKS) ? bsum[t] : 0;
    int x = v;
    #pragma unroll
    for (int off = 1; off < 64; off <<= 1) {
        int y = __shfl_up(x, off);
        if (t >= off) x += y;
    }
    if (t < NSCAN_BLKS) bsum[t] = x - v;   // exclusive
}

// ---------------------------------------------------------------- scan pass 3: full offsets
__global__ __launch_bounds__(1024) void scan3_kernel(const int* __restrict__ counts,
                                                     const int* __restrict__ bsum,
                                                     int* __restrict__ offsets) {
    __shared__ int wsum[16];
    __shared__ int wpre[16];
    const int t = threadIdx.x, lane = t & 63, wid = t >> 6;
    int i = blockIdx.x * 1024 + t;
    int v = (i < N_NODES) ? counts[i] : 0;
    int x = v;
    #pragma unroll
    for (int off = 1; off < 64; off <<= 1) {
        int y = __shfl_up(x, off);
        if (lane >= off) x += y;
    }
    if (lane == 63) wsum[wid] = x;
    __syncthreads();
    if (t < 16) {
        int p = 0;
        for (int j = 0; j < t; ++j) p += wsum[j];
        wpre[t] = p;
    }
    __syncthreads();
    int base = bsum[blockIdx.x];
    int incl = base + x + wpre[wid];
    if (i < N_NODES) offsets[i + 1] = incl;
    if (i == 0) offsets[0] = 0;
}

// ---------------------------------------------------------------- scatter edges into CSR order (atomic-free)
__global__ void scatter_kernel(const int* __restrict__ src, const int* __restrict__ dst,
                               const float* __restrict__ w, const int* __restrict__ offsets,
                               const int* __restrict__ erank,
                               unsigned int* __restrict__ ecmp) {
    int e = blockIdx.x * blockDim.x + threadIdx.x;
    if (e < N_EDGES) {
        int d = dst[e];
        int p = offsets[d] + erank[e];
        __half hw = __float2half(w[e]);
        ecmp[p] = ((unsigned int)__half_as_ushort(hw) << 16) | (unsigned int)src[e];
    }
}

// ---------------------------------------------------------------- fused weight prep:
// Bp = W_hop in MFMA B-fragment order (f16); WlW = W_lift@W_hop; blW = b_lift@W_hop
__global__ __launch_bounds__(256) void wprep_kernel(const float* __restrict__ W,
                                                    const float* __restrict__ Wl,
                                                    const float* __restrict__ bl,
                                                    _Float16* __restrict__ Bp,
                                                    float* __restrict__ WlW,
                                                    float* __restrict__ blW) {
    const int t = threadIdx.x;
    #pragma unroll
    for (int it = 0; it < 16; ++it) {
        int i = it * 256 + t;     // 0..4095
        int j  = i & 7;
        int l  = (i >> 3) & 63;
        int ks = (i >> 9) & 1;
        int w  = i >> 10;
        int k   = ks * 32 + ((j >> 2) * 16) + ((l >> 4) * 4) + (j & 3);
        int col = w * 16 + (l & 15);
        Bp[i] = (_Float16)W[k * 64 + col];
    }
    if (t < 64) {
        float a = 0.f, b = 0.f;
        #pragma unroll 8
        for (int h = 0; h < 64; ++h) {
            float wv = W[h * 64 + t];
            a += Wl[h] * wv;
            b += bl[h] * wv;
        }
        WlW[t] = a;
        blW[t] = b;
    }
}

// ---------------------------------------------------------------- hop-1 scalar gather: t[d,o]=sum w*nodes[s,o], u[d]=sum w
__global__ void hop1_gather_kernel(const int* __restrict__ offsets,
                                   const unsigned int* __restrict__ ecmp,
                                   const float* __restrict__ nodes,
                                   float4* __restrict__ T, float* __restrict__ U) {
    int n = blockIdx.x * blockDim.x + threadIdx.x;
    if (n >= N_NODES) return;
    int s = offsets[n], e = offsets[n + 1];
    float4 t = {0.f, 0.f, 0.f, 0.f};
    float u = 0.f;
    for (int i = s; i < e; ++i) {
        unsigned int p = ecmp[i];
        float w = __half2float(__ushort_as_half((unsigned short)(p >> 16)));
        int sn = (int)(p & 0xffffu);
        float4 nv = ((const float4*)nodes)[sn];
        t.x += w * nv.x; t.y += w * nv.y; t.z += w * nv.z; t.w += w * nv.w;
        u += w;
    }
    T[n] = t;
    U[n] = u;
}

// ---------------------------------------------------------------- hop-1 finish into obs-sliced X[o][n][h] f16
__global__ void hop1_finish_kernel(const float4* __restrict__ T, const float* __restrict__ U,
                                   const float* __restrict__ WlW, const float* __restrict__ blW,
                                   const float* __restrict__ bias, _Float16* __restrict__ X) {
    int i = blockIdx.x * blockDim.x + threadIdx.x;   // 4-elem group
    const int total = N_NODES * ROW / 4;
    if (i >= total) return;
    int n   = i >> 6;
    int rem = i & 63;
    int o   = rem >> 4;
    int h4  = rem & 15;
    float t = ((const float*)&T[n])[o];
    float u = U[n];
    float4 wv = ((const float4*)WlW)[h4];
    float4 bv = ((const float4*)blW)[h4];
    float4 hv = ((const float4*)bias)[h4];
    f16x4 st;
    st[0] = (_Float16)fmaxf(t * wv.x + u * bv.x + hv.x, 0.f);
    st[1] = (_Float16)fmaxf(t * wv.y + u * bv.y + hv.y, 0.f);
    st[2] = (_Float16)fmaxf(t * wv.z + u * bv.z + hv.z, 0.f);
    st[3] = (_Float16)fmaxf(t * wv.w + u * bv.w + hv.w, 0.f);
    *(f16x4*)(X + ((size_t)o * N_NODES + n) * 64 + h4 * 4) = st;
}

// ---------------------------------------------------------------- fused hop (R13 structure, best verified):
// obs-sliced X [4][N][64 f16] (128B rows); blockIdx&7 -> XCD, obs = xcd>>1.
// Block = 32 nodes x 1 obs; 8 lanes/node, unroll-8 edge rounds (8 row loads
// in flight); pk_fma f16 accum; 16 MFMAs/block; LDS-staged coalesced epilogue.
template<int LAST>
__global__ __launch_bounds__(256) void hop_kernel(const int* __restrict__ offsets,
                                                  const unsigned int* __restrict__ ecmp,
                                                  const _Float16* __restrict__ Xin,
                                                  const _Float16* __restrict__ Bp,
                                                  const float* __restrict__ bias,
                                                  _Float16* __restrict__ Xout,
                                                  float* __restrict__ Fout) {
    __shared__ __align__(16) char smem[32 * 68 * 4];     // 8704 B, aliased
    _Float16 (*As)[72]  = (_Float16(*)[72])smem;         // gather stage + f16 epilogue
    float    (*Asf)[68] = (float(*)[68])smem;            // f32 epilogue (LAST)

    const int t = threadIdx.x;
    const int wid = t >> 6, lane = t & 63;
    const int b = blockIdx.x;
    const int xcd = b & 7;
    const int o = xcd >> 1;                  // obs slice pinned to XCD pair
    const int g = ((b >> 3) << 1) | (xcd & 1);
    const int n0 = g * 32;
    if (n0 >= N_NODES) return;

    const int g8  = lane >> 3;               // node group within wave (0..7)
    const int sub = lane & 7;                // 16B chunk of the 128B row
    const int local = wid * 8 + g8;          // 0..31
    const int node = n0 + local;
    const int nc = (node < N_NODES) ? node : N_NODES - 1;
    int sN = offsets[nc];
    int eN = offsets[nc + 1];
    if (node >= N_NODES) eN = sN;
    const int deg = eN - sN;

    const _Float16* __restrict__ Xb = Xin + (size_t)o * (N_NODES * 64);

    f16x8 acc0 = (f16x8)(_Float16)0.0f;
    f16x8 acc1 = (f16x8)(_Float16)0.0f;

    for (int base = 0; base < deg; base += 8) {
        f16x8 r[8];
        _Float16 wh[8];
        #pragma unroll
        for (int q = 0; q < 8; ++q) {
            int idx = base + q;
            int e = sN + ((idx < deg) ? idx : 0);    // clamped: pad slots reload edge 0
            unsigned int p = ecmp[e];
            unsigned short wu = (idx < deg) ? (unsigned short)(p >> 16) : (unsigned short)0;
            wh[q] = __builtin_bit_cast(_Float16, wu);
            r[q] = *(const f16x8*)(Xb + (int)(p & 0xffffu) * 64 + sub * 8);
        }
        #pragma unroll
        for (int q = 0; q < 8; q += 2) {
            acc0 += r[q]     * wh[q];
            acc1 += r[q + 1] * wh[q + 1];
        }
    }
    acc0 += acc1;
    *(f16x8*)&As[local][sub * 8] = acc0;
    __syncthreads();

    // wave: node-tile nt = wid>>1 (16 nodes), col-tiles ct0, ct0+1 (32 hid)
    const int r15 = lane & 15, gq = lane >> 4;
    const int nt  = wid >> 1;
    const int ct0 = (wid & 1) * 2;
    const int arow = nt * 16 + r15;
    f16x8 a0, a1;
    ((f16x4*)&a0)[0] = *(const f16x4*)&As[arow][ 0 + 4 * gq];
    ((f16x4*)&a0)[1] = *(const f16x4*)&As[arow][16 + 4 * gq];
    ((f16x4*)&a1)[0] = *(const f16x4*)&As[arow][32 + 4 * gq];
    ((f16x4*)&a1)[1] = *(const f16x4*)&As[arow][48 + 4 * gq];
    float res[2][4];
    #pragma unroll
    for (int c = 0; c < 2; ++c) {
        const int ct = ct0 + c;
        f16x8 b0 = *(const f16x8*)(Bp + ((size_t)(ct * 2 + 0) * 64 + lane) * 8);
        f16x8 b1 = *(const f16x8*)(Bp + ((size_t)(ct * 2 + 1) * 64 + lane) * 8);
        f32x4 cc = {0.f, 0.f, 0.f, 0.f};
        cc = __builtin_amdgcn_mfma_f32_16x16x32_f16(a0, b0, cc, 0, 0, 0);
        cc = __builtin_amdgcn_mfma_f32_16x16x32_f16(a1, b1, cc, 0, 0, 0);
        const float bv = bias[ct * 16 + r15];
        #pragma unroll
        for (int j = 0; j < 4; ++j) res[c][j] = fmaxf(cc[j] + bv, 0.f);
    }
    __syncthreads();   // all frag loads done; safe to overwrite LDS

    // stage results: row = local node (nt*16+gq*4+j), col = h (ct*16+r15)
    #pragma unroll
    for (int c = 0; c < 2; ++c) {
        const int h = (ct0 + c) * 16 + r15;
        #pragma unroll
        for (int j = 0; j < 4; ++j) {
            int ln = nt * 16 + gq * 4 + j;
            if (LAST) Asf[ln][h] = res[c][j];
            else      As[ln][h]  = (_Float16)res[c][j];
        }
    }
    __syncthreads();

    // coalesced write-out: 8 lanes per node row
    const int wl = t >> 3;       // local node 0..31
    const int wsc = t & 7;       // 8-elem chunk
    const int wnode = n0 + wl;
    if (wnode < N_NODES) {
        if (LAST) {
            float4 v0 = *(const float4*)&Asf[wl][wsc * 8];
            float4 v1 = *(const float4*)&Asf[wl][wsc * 8 + 4];
            float* dst = Fout + (size_t)wnode * ROW + o * 64 + wsc * 8;
            *(float4*)dst       = v0;
            *(float4*)(dst + 4) = v1;
        } else {
            f16x8 v = *(const f16x8*)&As[wl][wsc * 8];
            *(f16x8*)(Xout + ((size_t)o * N_NODES + wnode) * 64 + wsc * 8) = v;
        }
    }
}

// ---------------------------------------------------------------- launch
extern "C" void kernel_launch(void* const* d_in, const int* in_sizes, int n_in,
                              void* d_out, int out_size, void* d_ws, size_t ws_size,
                              hipStream_t stream) {
    const float* nodes   = (const float*)d_in[0];
    const int*   esrc    = (const int*)d_in[1];
    const int*   edst    = (const int*)d_in[2];
    const float* eweight = (const float*)d_in[3];
    const float* W_lift  = (const float*)d_in[4];
    const float* b_lift  = (const float*)d_in[5];
    const float* W_hop   = (const float*)d_in[6];
    const float* b_hop   = (const float*)d_in[7];

    char* ws = (char*)d_ws;
    _Float16*     X0   = (_Float16*)(ws);                    // 25,600,000 B
    _Float16*     X1   = (_Float16*)(ws + 25600000);         // 25,600,000 B
    unsigned int* ECMP = (unsigned int*)(ws + 51200000);     //  3,200,000 B
    int*          OFF  = (int*)(ws + 54400000);              //    200,064 B
    int*          CNT  = (int*)(ws + 54600064);              //    200,000 B
    int*          BSUM = (int*)(ws + 54800064);              //        256 B
    _Float16*     BP   = (_Float16*)(ws + 54800320);         //      8,192 B
    float*        WLW  = (float*)(ws + 54808512);            //        256 B
    float*        BLW  = (float*)(ws + 54808768);            //        256 B
    // ERANK overlays T/U (disjoint lifetimes: ERANK dead after scatter)
    int*          ERANK = (int*)(ws + 54809024);             //  3,200,000 B
    float4*       T    = (float4*)(ws + 54809024);           //    800,000 B
    float*        U    = (float*)(ws + 55609024);            //    200,000 B

    // CSR build: hist computes per-edge rank; scatter is atomic-free
    zero_kernel<<<(N_NODES + 255) / 256, 256, 0, stream>>>(CNT, N_NODES);
    hist_kernel<<<(N_EDGES + 255) / 256, 256, 0, stream>>>(edst, CNT, ERANK);
    scan1_kernel<<<NSCAN_BLKS, 1024, 0, stream>>>(CNT, BSUM);
    scan2_kernel<<<1, 64, 0, stream>>>(BSUM);
    scan3_kernel<<<NSCAN_BLKS, 1024, 0, stream>>>(CNT, BSUM, OFF);
    scatter_kernel<<<(N_EDGES + 255) / 256, 256, 0, stream>>>(esrc, edst, eweight, OFF, ERANK, ECMP);

    // fused weight prep
    wprep_kernel<<<1, 256, 0, stream>>>(W_hop, W_lift, b_lift, BP, WLW, BLW);

    // hop 1 (algebraic: scalar gather + rank-1 reconstruction) -> X0 (obs-sliced)
    hop1_gather_kernel<<<(N_NODES + 255) / 256, 256, 0, stream>>>(OFF, ECMP, nodes, T, U);
    hop1_finish_kernel<<<(N_NODES * ROW / 4 + 255) / 256, 256, 0, stream>>>(T, U, WLW, BLW, b_hop, X0);

    // hops 2..5: fused obs-sliced gather+GEMM, double-buffered X
    const int hopGrid = 8 * 782;   // xcd-pinned: 4 obs x 1564 half-groups (32 nodes/blk)
    _Float16* Xi = X0;
    _Float16* Xo = X1;
    for (int hop = 1; hop < K_HOPS; ++hop) {
        if (hop == K_HOPS - 1) {
            hop_kernel<1><<<hopGrid, 256, 0, stream>>>(OFF, ECMP, Xi, BP, b_hop,
                                                       nullptr, (float*)d_out);
        } else {
            hop_kernel<0><<<hopGrid, 256, 0, stream>>>(OFF, ECMP, Xi, BP, b_hop,
                                                       Xo, nullptr);
        }
        _Float16* tmp = Xi; Xi = Xo; Xo = tmp;
    }
}